// Round 1
// baseline (331.964 us; speedup 1.0000x reference)
//
#include <hip/hip_runtime.h>
#include <hip/hip_bf16.h>
#include <stdint.h>

#define B_ 256
#define H_ 4096
#define K_ 32768   // V*N = 1024*32

typedef __attribute__((ext_vector_type(8))) short bf16x8;
typedef __attribute__((ext_vector_type(4))) float f32x4;

__device__ __forceinline__ unsigned short f2bf(float x) {
    union { float f; unsigned int u; } c; c.f = x;
    unsigned int r = c.u + 0x7FFFu + ((c.u >> 16) & 1u);  // RNE
    return (unsigned short)(r >> 16);
}

__device__ __forceinline__ float softplus_f(float x) {
    return fmaxf(x, 0.0f) + log1pf(expf(-fabsf(x)));
}

// ---------------- Kernel A: v fp32->bf16 + vt[b] = dot(v[b,:], b_v) ----------------
__global__ __launch_bounds__(256) void prep_kernel(
    const float* __restrict__ v, const float* __restrict__ bv,
    __hip_bfloat16* __restrict__ vbf, float* __restrict__ vt)
{
    const int b = blockIdx.x;
    const int t = threadIdx.x;
    const float* vr = v + (size_t)b * K_;
    unsigned short* dr = (unsigned short*)(vbf + (size_t)b * K_);
    float acc = 0.f;
    for (int i = t * 8; i < K_; i += 256 * 8) {
        float4 x0 = *(const float4*)(vr + i);
        float4 x1 = *(const float4*)(vr + i + 4);
        float4 b0 = *(const float4*)(bv + i);
        float4 b1 = *(const float4*)(bv + i + 4);
        acc += x0.x*b0.x + x0.y*b0.y + x0.z*b0.z + x0.w*b0.w
             + x1.x*b1.x + x1.y*b1.y + x1.z*b1.z + x1.w*b1.w;
        ushort4 u0, u1;
        u0.x = f2bf(x0.x); u0.y = f2bf(x0.y); u0.z = f2bf(x0.z); u0.w = f2bf(x0.w);
        u1.x = f2bf(x1.x); u1.y = f2bf(x1.y); u1.z = f2bf(x1.z); u1.w = f2bf(x1.w);
        *(ushort4*)(dr + i)     = u0;
        *(ushort4*)(dr + i + 4) = u1;
    }
    __shared__ float sm[256];
    sm[t] = acc;
    __syncthreads();
    for (int s = 128; s > 0; s >>= 1) {
        if (t < s) sm[t] += sm[t + s];
        __syncthreads();
    }
    if (t == 0) vt[b] = sm[0];
}

// ---------------- Kernel B: split-K GEMM, BM=256 BN=64 BK=64, 8 waves (4Mx2N) ----------------
// A = v (bf16, staged via global_load_lds with source pre-swizzle)
// B = W (fp32, direct global->reg per wave, converted to bf16 in-reg)
// partials[s][b][h] fp32 written to workspace (no atomics -> deterministic).

#define STAGE_A(bufi, kt)  do {                                                        \
    _Pragma("unroll")                                                                  \
    for (int i_ = 0; i_ < 4; ++i_) {                                                   \
        __builtin_amdgcn_global_load_lds(                                              \
            (const __attribute__((address_space(1))) unsigned int*)(asrc[i_] + (size_t)(kt) * 64), \
            (__attribute__((address_space(3))) unsigned int*)(&abuf[(bufi)][aldsoff[i_]]), \
            16, 0, 0);                                                                 \
    } } while (0)

#define LOAD_W(kt) do {                                                                \
    _Pragma("unroll")                                                                  \
    for (int n_ = 0; n_ < 2; ++n_) {                                                   \
      _Pragma("unroll")                                                                \
      for (int s_ = 0; s_ < 2; ++s_) {                                                 \
        const float* p_ = wrow[n_] + (size_t)(kt) * 64 + s_ * 32;                      \
        wr[n_][s_][0] = *(const float4*)p_;                                            \
        wr[n_][s_][1] = *(const float4*)(p_ + 4);                                      \
      } } } while (0)

#define CVT_W() do {                                                                   \
    _Pragma("unroll")                                                                  \
    for (int n_ = 0; n_ < 2; ++n_) {                                                   \
      _Pragma("unroll")                                                                \
      for (int s_ = 0; s_ < 2; ++s_) {                                                 \
        bf16x8 t_;                                                                     \
        t_[0] = (short)f2bf(wr[n_][s_][0].x); t_[1] = (short)f2bf(wr[n_][s_][0].y);    \
        t_[2] = (short)f2bf(wr[n_][s_][0].z); t_[3] = (short)f2bf(wr[n_][s_][0].w);    \
        t_[4] = (short)f2bf(wr[n_][s_][1].x); t_[5] = (short)f2bf(wr[n_][s_][1].y);    \
        t_[6] = (short)f2bf(wr[n_][s_][1].z); t_[7] = (short)f2bf(wr[n_][s_][1].w);    \
        bfr[n_][s_] = t_;                                                              \
      } } } while (0)

__global__ __launch_bounds__(512, 4) void gemm_kernel(
    const __hip_bfloat16* __restrict__ vbf,   // [256][32768] bf16
    const float* __restrict__ W,              // [4096][32768] fp32
    float* __restrict__ part,                 // [KS][256][4096] fp32
    int KS, int NT)                           // NT = (K_/KS)/64
{
    __shared__ __align__(16) __hip_bfloat16 abuf[2][256 * 64];  // 2 x 32 KB

    const int tid  = threadIdx.x;
    const int wid  = tid >> 6;
    const int lane = tid & 63;
    const int lr   = lane & 15;   // row-in-16 for frags / n,m index
    const int lg   = lane >> 4;   // k-granule 0..3

    const int bid   = blockIdx.x;
    const int sidx  = bid % KS;   // k-split id: == XCD id when KS==8 (L2 locality for v slice)
    const int ht    = bid / KS;
    const int h0    = ht * 64;
    const int kbase = sidx * (NT * 64);

    const int wm = wid & 3;       // wave M index (4): 64 rows each
    const int wn = wid >> 2;      // wave N index (2): 32 cols each

    // W row base pointers for the 2 n-reps of this wave (B-frag: n = lr, k = lg*8 + j)
    const float* wrow[2];
    wrow[0] = W + (size_t)(h0 + wn * 32 +  0 + lr) * K_ + kbase + lg * 8;
    wrow[1] = W + (size_t)(h0 + wn * 32 + 16 + lr) * K_ + kbase + lg * 8;

    // A staging: LDS linear granule (row,g) gets global granule (g ^ (row&7))
    // (pre-swizzled SOURCE + swizzled READ; LDS dest stays linear for global_load_lds)
    const __hip_bfloat16* asrc[4];
    int aldsoff[4];
    #pragma unroll
    for (int i = 0; i < 4; ++i) {
        int flat = i * 512 + tid;
        int row  = flat >> 3;
        int g    = flat & 7;
        asrc[i]    = vbf + (size_t)row * K_ + kbase + ((g ^ (row & 7)) << 3);
        aldsoff[i] = (i * 512 + wid * 64) * 8;   // wave-uniform element offset
    }

    f32x4 acc[4][2];
    #pragma unroll
    for (int m = 0; m < 4; ++m)
        #pragma unroll
        for (int n = 0; n < 2; ++n)
            acc[m][n] = (f32x4)(0.0f);

    float4 wr[2][2][2];   // raw W fp32 [nrep][slice][half]
    bf16x8 bfr[2][2];     // converted B-frags [nrep][slice]

    STAGE_A(0, 0);
    LOAD_W(0);
    __syncthreads();      // drains vmcnt(0): A(0) in LDS for all waves

    for (int kt = 0; kt < NT; ++kt) {
        const int cur = kt & 1;
        CVT_W();                          // consume wr(kt) -> bfr
        if (kt + 1 < NT) {
            STAGE_A(cur ^ 1, kt + 1);     // async v -> other LDS buffer
            LOAD_W(kt + 1);               // W fp32 -> regs (overlaps compute below)
        }
        #pragma unroll
        for (int s = 0; s < 2; ++s) {
            bf16x8 a[4];
            #pragma unroll
            for (int m = 0; m < 4; ++m) {
                int row = wm * 64 + m * 16 + lr;
                int g   = s * 4 + lg;
                int off = row * 64 + ((g ^ (row & 7)) << 3);
                a[m] = *(const bf16x8*)&abuf[cur][off];   // ds_read_b128, 2-way (free)
            }
            #pragma unroll
            for (int m = 0; m < 4; ++m)
                #pragma unroll
                for (int n = 0; n < 2; ++n)
                    acc[m][n] = __builtin_amdgcn_mfma_f32_16x16x32_bf16(
                        a[m], bfr[n][s], acc[m][n], 0, 0, 0);
        }
        __syncthreads();  // next-buffer staging complete for all waves
    }

    // Epilogue: C/D layout col=lane&15 (=h), row=(lane>>4)*4+reg (=b)
    float* pout = part + (size_t)sidx * ((size_t)B_ * H_) + h0;
    #pragma unroll
    for (int m = 0; m < 4; ++m)
        #pragma unroll
        for (int n = 0; n < 2; ++n)
            #pragma unroll
            for (int j = 0; j < 4; ++j) {
                int brow = wm * 64 + m * 16 + lg * 4 + j;
                int hcol = wn * 32 + n * 16 + lr;
                pout[(size_t)brow * H_ + hcol] = acc[m][n][j];
            }
}

// ---------------- Kernel C: reduce splits + b_h, softplus, sum over H, + vt ----------------
__global__ __launch_bounds__(256) void reduce_kernel(
    const float* __restrict__ part, const float* __restrict__ bh,
    const float* __restrict__ vt, float* __restrict__ out, int KS)
{
    const int b = blockIdx.x;
    const int t = threadIdx.x;
    float sp = 0.f;
    const float* pb = part + (size_t)b * H_;
    for (int h = t * 4; h < H_; h += 256 * 4) {
        float4 l = *(const float4*)(bh + h);
        for (int s = 0; s < KS; ++s) {
            float4 p = *(const float4*)(pb + (size_t)s * B_ * H_ + h);
            l.x += p.x; l.y += p.y; l.z += p.z; l.w += p.w;
        }
        sp += softplus_f(l.x) + softplus_f(l.y) + softplus_f(l.z) + softplus_f(l.w);
    }
    __shared__ float sm[256];
    sm[t] = sp;
    __syncthreads();
    for (int r = 128; r > 0; r >>= 1) {
        if (t < r) sm[t] += sm[t + r];
        __syncthreads();
    }
    if (t == 0) out[b] = sm[0] + vt[b];
}

extern "C" void kernel_launch(void* const* d_in, const int* in_sizes, int n_in,
                              void* d_out, int out_size, void* d_ws, size_t ws_size,
                              hipStream_t stream)
{
    const float* v  = (const float*)d_in[0];
    const float* W  = (const float*)d_in[1];
    const float* bh = (const float*)d_in[2];
    const float* bv = (const float*)d_in[3];
    float* out = (float*)d_out;

    char* ws = (char*)d_ws;
    const size_t vbf_bytes = (size_t)B_ * K_ * sizeof(__hip_bfloat16);  // 16 MB
    __hip_bfloat16* vbf = (__hip_bfloat16*)ws;

    int KS = 8;                                   // shrink if workspace is small
    while (KS > 1 && vbf_bytes + (size_t)KS * B_ * H_ * 4 + 1024 > ws_size) KS >>= 1;

    float* part = (float*)(ws + vbf_bytes);                                  // KS*4 MB
    float* vt   = (float*)(ws + vbf_bytes + (size_t)KS * B_ * H_ * 4);       // 1 KB

    prep_kernel<<<B_, 256, 0, stream>>>(v, bv, vbf, vt);
    const int NT = (K_ / KS) / 64;
    gemm_kernel<<<64 * KS, 512, 0, stream>>>(vbf, W, part, KS, NT);
    reduce_kernel<<<B_, 256, 0, stream>>>(part, bh, vt, out, KS);
}

// Round 3
// 203.261 us; speedup vs baseline: 1.6332x; 1.6332x over previous
//
#include <hip/hip_runtime.h>
#include <hip/hip_bf16.h>
#include <stdint.h>

#define B_ 256
#define H_ 4096
#define K_ 32768   // V*N = 1024*32

typedef __attribute__((ext_vector_type(8))) short bf16x8;
typedef __attribute__((ext_vector_type(4))) float f32x4;

__device__ __forceinline__ unsigned short f2bf(float x) {
    union { float f; unsigned int u; } c; c.f = x;
    unsigned int r = c.u + 0x7FFFu + ((c.u >> 16) & 1u);  // RNE
    return (unsigned short)(r >> 16);
}

__device__ __forceinline__ short bfc(float x) {
    __hip_bfloat16 h = __float2bfloat16(x);
    union { __hip_bfloat16 h; short s; } c; c.h = h;
    return c.s;
}

__device__ __forceinline__ float softplus_f(float x) {
    return fmaxf(x, 0.0f) + log1pf(expf(-fabsf(x)));
}

// ---------------- Kernel A: v fp32->bf16 + vt[b] = dot(v[b,:], b_v) ----------------
__global__ __launch_bounds__(256) void prep_kernel(
    const float* __restrict__ v, const float* __restrict__ bv,
    __hip_bfloat16* __restrict__ vbf, float* __restrict__ vt)
{
    const int b = blockIdx.x;
    const int t = threadIdx.x;
    const float* vr = v + (size_t)b * K_;
    unsigned short* dr = (unsigned short*)(vbf + (size_t)b * K_);
    float acc = 0.f;
    for (int i = t * 8; i < K_; i += 256 * 8) {
        float4 x0 = *(const float4*)(vr + i);
        float4 x1 = *(const float4*)(vr + i + 4);
        float4 b0 = *(const float4*)(bv + i);
        float4 b1 = *(const float4*)(bv + i + 4);
        acc += x0.x*b0.x + x0.y*b0.y + x0.z*b0.z + x0.w*b0.w
             + x1.x*b1.x + x1.y*b1.y + x1.z*b1.z + x1.w*b1.w;
        ushort4 u0, u1;
        u0.x = f2bf(x0.x); u0.y = f2bf(x0.y); u0.z = f2bf(x0.z); u0.w = f2bf(x0.w);
        u1.x = f2bf(x1.x); u1.y = f2bf(x1.y); u1.z = f2bf(x1.z); u1.w = f2bf(x1.w);
        *(ushort4*)(dr + i)     = u0;
        *(ushort4*)(dr + i + 4) = u1;
    }
    __shared__ float sm[256];
    sm[t] = acc;
    __syncthreads();
    for (int s = 128; s > 0; s >>= 1) {
        if (t < s) sm[t] += sm[t + s];
        __syncthreads();
    }
    if (t == 0) vt[b] = sm[0];
}

// ---------------- Kernel B: split-K GEMM, BM=256 BN=64 BK=64 ----------------
// Depth-4 LDS ring for W (fp32, global_load_lds, XOR-swizzled source + swizzled read),
// A (v bf16, L2-resident) direct global->reg, double-buffered 1 iter ahead.
// ONE fused {s_waitcnt vmcnt(N); s_barrier} asm per K-step; vmcnt never 0 in main loop.
//
// Per-wave vmem FIFO (A-tile = 4x global_load_dwordx4, W-tile = 2x global_load_lds):
//   at BODY(t) wait: outstanding <= W(t)2 A(t)4 W(t+1)2 A(t+1)4 W(t+2)2 = 14
//   vmcnt(8) frees oldest 6 = W(t)+A(t); W(t+1),A(t+1),W(t+2) stay in flight.
//   Tail: BODY(NT-2) -> vmcnt(6); BODY(NT-1) -> vmcnt(0).
// Ring safety (1 barrier/iter, max skew 1 iter): writes target slots (t+2)&3/(t+3)&3,
// concurrent reads target slots t&3/(t+1)&3 -> disjoint mod 4.

#define STAGE_W(slot, kt) do {                                                         \
    _Pragma("unroll")                                                                  \
    for (int p_ = 0; p_ < 2; ++p_) {                                                   \
        __builtin_amdgcn_global_load_lds(                                              \
            (const __attribute__((address_space(1))) unsigned int*)(wsrc[p_] + (size_t)(kt) * 64), \
            (__attribute__((address_space(3))) unsigned int*)(&wbuf[(slot)][wldsoff[p_]]), \
            16, 0, 0);                                                                 \
    } } while (0)

#define LOAD_A(dst, kt) do {                                                           \
    _Pragma("unroll")                                                                  \
    for (int m_ = 0; m_ < 2; ++m_)                                                     \
      _Pragma("unroll")                                                                \
      for (int s_ = 0; s_ < 2; ++s_)                                                   \
        dst[m_*2+s_] = *(const bf16x8*)(ap[m_] + (size_t)(kt) * 64 + s_ * 32);         \
    } while (0)

#define COMPUTE(AUSE, T_) do {                                                         \
    const float* wb_ = &wbuf[(T_) & 3][0];                                             \
    _Pragma("unroll")                                                                  \
    for (int s_ = 0; s_ < 2; ++s_) {                                                   \
      bf16x8 bfr[4];                                                                   \
      _Pragma("unroll")                                                                \
      for (int n_ = 0; n_ < 4; ++n_) {                                                 \
        int row_ = n_ * 16 + lr;                                                       \
        int m7_  = row_ & 7;                                                           \
        int g0_  = s_ * 8 + lg * 2;                                                    \
        float4 lo_ = *(const float4*)&wb_[row_ * 64 + (((g0_    ) ^ m7_) << 2)];       \
        float4 hi_ = *(const float4*)&wb_[row_ * 64 + (((g0_ + 1) ^ m7_) << 2)];       \
        bf16x8 t_;                                                                     \
        t_[0]=bfc(lo_.x); t_[1]=bfc(lo_.y); t_[2]=bfc(lo_.z); t_[3]=bfc(lo_.w);        \
        t_[4]=bfc(hi_.x); t_[5]=bfc(hi_.y); t_[6]=bfc(hi_.z); t_[7]=bfc(hi_.w);        \
        bfr[n_] = t_;                                                                  \
      }                                                                                \
      _Pragma("unroll")                                                                \
      for (int m_ = 0; m_ < 2; ++m_)                                                   \
        _Pragma("unroll")                                                              \
        for (int n_ = 0; n_ < 4; ++n_)                                                 \
          acc[m_][n_] = __builtin_amdgcn_mfma_f32_16x16x32_bf16(                       \
              AUSE[m_*2+s_], bfr[n_], acc[m_][n_], 0, 0, 0);                           \
    } } while (0)

// Fused wait+barrier in ONE asm: no memory op (incl. COMPUTE ds_reads) can be
// scheduled between the waitcnt and the barrier, and none cross it either way.
#define WAIT_BAR(VMSTR) \
    asm volatile("s_waitcnt " VMSTR "\n\ts_barrier" ::: "memory")

#define BODY(T_, AUSE, ALOAD, ISSW, ISSA, VMSTR) do {                                  \
    if (ISSA) LOAD_A(ALOAD, (T_) + 1);                                                 \
    if (ISSW) STAGE_W(((T_) + 2) & 3, (T_) + 2);                                       \
    WAIT_BAR(VMSTR);                                                                   \
    COMPUTE(AUSE, T_);                                                                 \
    } while (0)

__global__ __launch_bounds__(512, 2) void gemm_kernel(
    const __hip_bfloat16* __restrict__ vbf,   // [256][32768] bf16
    const float* __restrict__ W,              // [4096][32768] fp32
    float* __restrict__ part,                 // [KS][256][4096] fp32
    int KS, int NT)                           // NT = (K_/KS)/64, even, >= 4
{
    __shared__ __align__(16) float wbuf[4][64 * 64];   // 4 x 16 KB ring

    const int tid  = threadIdx.x;
    const int wid  = tid >> 6;
    const int lane = tid & 63;
    const int lr   = lane & 15;   // B-frag n / A-frag row-in-16
    const int lg   = lane >> 4;   // k-granule 0..3

    const int bid   = blockIdx.x;
    const int sidx  = bid % KS;   // k-split; == XCD id when KS==8 (v-slice L2 locality)
    const int ht    = bid / KS;
    const int h0    = ht * 64;
    const int kbase = sidx * (NT * 64);

    // W staging: LDS linear granule (row, g') holds global granule g = g' ^ (row&7)
    const float* wsrc[2];
    int wldsoff[2];
    #pragma unroll
    for (int p = 0; p < 2; ++p) {
        int f   = p * 512 + tid;
        int row = f >> 4;       // 0..63
        int gl  = f & 15;       // linear 16B granule in row
        int g   = gl ^ (row & 7);
        wsrc[p]    = W + (size_t)(h0 + row) * K_ + kbase + g * 4;
        wldsoff[p] = (p * 512 + wid * 64) * 4;   // float idx, wave-uniform base
    }

    // A: this wave owns rows wid*32 .. wid*32+31
    const __hip_bfloat16* ap[2];
    #pragma unroll
    for (int m = 0; m < 2; ++m)
        ap[m] = vbf + (size_t)(wid * 32 + m * 16 + lr) * K_ + kbase + lg * 8;

    f32x4 acc[2][4];
    #pragma unroll
    for (int m = 0; m < 2; ++m)
        #pragma unroll
        for (int n = 0; n < 4; ++n)
            acc[m][n] = (f32x4)(0.0f);

    bf16x8 aA[4], aB[4];

    // Prologue: A(0), W(0), W(1), then a compiler memory fence so BODY(0)'s
    // issues cannot be interleaved before these (keeps the oldest-6 set exact).
    LOAD_A(aA, 0);
    STAGE_W(0, 0);
    STAGE_W(1, 1);
    asm volatile("" ::: "memory");

    for (int t = 0; t < NT - 2; t += 2) {
        BODY(t,     aA, aB, true, true, "vmcnt(8)");
        BODY(t + 1, aB, aA, true, true, "vmcnt(8)");
    }
    BODY(NT - 2, aA, aB, false, true,  "vmcnt(6)");
    BODY(NT - 1, aB, aA, false, false, "vmcnt(0)");

    // Epilogue: C/D layout col=lane&15 (=h), row=(lane>>4)*4+reg (=b)
    float* pout = part + (size_t)sidx * ((size_t)B_ * H_) + h0;
    #pragma unroll
    for (int m = 0; m < 2; ++m)
        #pragma unroll
        for (int n = 0; n < 4; ++n)
            #pragma unroll
            for (int j = 0; j < 4; ++j) {
                int brow = wid * 32 + m * 16 + lg * 4 + j;
                int hcol = n * 16 + lr;
                pout[(size_t)brow * H_ + hcol] = acc[m][n][j];
            }
}

// ---------------- Kernel C: reduce splits + b_h, softplus, sum over H, + vt ----------------
__global__ __launch_bounds__(256) void reduce_kernel(
    const float* __restrict__ part, const float* __restrict__ bh,
    const float* __restrict__ vt, float* __restrict__ out, int KS)
{
    const int b = blockIdx.x;
    const int t = threadIdx.x;
    float sp = 0.f;
    const float* pb = part + (size_t)b * H_;
    for (int h = t * 4; h < H_; h += 256 * 4) {
        float4 l = *(const float4*)(bh + h);
        for (int s = 0; s < KS; ++s) {
            float4 p = *(const float4*)(pb + (size_t)s * B_ * H_ + h);
            l.x += p.x; l.y += p.y; l.z += p.z; l.w += p.w;
        }
        sp += softplus_f(l.x) + softplus_f(l.y) + softplus_f(l.z) + softplus_f(l.w);
    }
    __shared__ float sm[256];
    sm[t] = sp;
    __syncthreads();
    for (int r = 128; r > 0; r >>= 1) {
        if (t < r) sm[t] += sm[t + r];
        __syncthreads();
    }
    if (t == 0) out[b] = sm[0] + vt[b];
}

extern "C" void kernel_launch(void* const* d_in, const int* in_sizes, int n_in,
                              void* d_out, int out_size, void* d_ws, size_t ws_size,
                              hipStream_t stream)
{
    const float* v  = (const float*)d_in[0];
    const float* W  = (const float*)d_in[1];
    const float* bh = (const float*)d_in[2];
    const float* bv = (const float*)d_in[3];
    float* out = (float*)d_out;

    char* ws = (char*)d_ws;
    const size_t vbf_bytes = (size_t)B_ * K_ * sizeof(__hip_bfloat16);  // 16 MB
    __hip_bfloat16* vbf = (__hip_bfloat16*)ws;

    int KS = 8;                                   // shrink if workspace is small
    while (KS > 1 && vbf_bytes + (size_t)KS * B_ * H_ * 4 + 1024 > ws_size) KS >>= 1;

    float* part = (float*)(ws + vbf_bytes);                                  // KS*4 MB
    float* vt   = (float*)(ws + vbf_bytes + (size_t)KS * B_ * H_ * 4);       // 1 KB

    prep_kernel<<<B_, 256, 0, stream>>>(v, bv, vbf, vt);
    const int NT = (K_ / KS) / 64;                // 64 for KS=8 (even, >=4)
    gemm_kernel<<<(H_ / 64) * KS, 512, 0, stream>>>(vbf, W, part, KS, NT);
    reduce_kernel<<<B_, 256, 0, stream>>>(part, bh, vt, out, KS);
}